// Round 2
// baseline (1115.760 us; speedup 1.0000x reference)
//
#include <hip/hip_runtime.h>

#define BB 2
#define LL 2048
#define DD 1024
#define HH 16
#define DHD 64

typedef __attribute__((ext_vector_type(8))) short bf16x8;
typedef __attribute__((ext_vector_type(4))) float f32x4;
typedef unsigned long long ull;

#define MFMA16(a, b, c) __builtin_amdgcn_mfma_f32_16x16x32_bf16((a), (b), (c), 0, 0, 0)

__device__ __forceinline__ unsigned short f2bf(float f) {
    union { float f; unsigned u; } c; c.f = f;
    unsigned r = 0x7FFFu + ((c.u >> 16) & 1u);
    return (unsigned short)((c.u + r) >> 16);
}
__device__ __forceinline__ ull pack4(float x, float y, float z, float w) {
    return (ull)f2bf(x) | ((ull)f2bf(y) << 16) | ((ull)f2bf(z) << 32) | ((ull)f2bf(w) << 48);
}

// C = A(MxK) * B(KxN). A,B,C fp32; internally bf16 MFMA with fp32 accumulate.
// 64x64 block tile, BK=64, 256 threads = 4 waves, each wave 32x32.
__global__ __launch_bounds__(256) void gemm_f32(
    const float* __restrict__ A, const float* __restrict__ B,
    float* __restrict__ C, int M, int N, int K)
{
    __shared__ unsigned short As[64][72];
    __shared__ unsigned short Bs[64][72];  // Bs[n][k] (transposed)
    const int tid  = threadIdx.x;
    const int lane = tid & 63, wave = tid >> 6;
    const int l15  = lane & 15, quad = lane >> 4;
    const int m0 = blockIdx.y * 64, n0 = blockIdx.x * 64;
    const int wm = (wave >> 1) * 32, wn = (wave & 1) * 32;

    f32x4 acc[2][2];
#pragma unroll
    for (int i = 0; i < 2; ++i)
#pragma unroll
        for (int j = 0; j < 2; ++j) acc[i][j] = (f32x4){0.f, 0.f, 0.f, 0.f};

    for (int k0 = 0; k0 < K; k0 += 64) {
        // stage A tile: fp32 float4 load -> bf16x4 LDS store (4 per thread)
#pragma unroll
        for (int i = 0; i < 4; ++i) {
            int v = tid + i * 256;          // 0..1023
            int row = v >> 4, col = (v & 15) * 4;
            float4 f = *(const float4*)&A[(size_t)(m0 + row) * K + k0 + col];
            *(ull*)&As[row][col] = pack4(f.x, f.y, f.z, f.w);
        }
        // stage B tile transposed
#pragma unroll
        for (int i = 0; i < 4; ++i) {
            int v = tid + i * 256;
            int kk = v >> 4, nn = (v & 15) * 4;
            float4 f = *(const float4*)&B[(size_t)(k0 + kk) * N + n0 + nn];
            Bs[nn + 0][kk] = f2bf(f.x);
            Bs[nn + 1][kk] = f2bf(f.y);
            Bs[nn + 2][kk] = f2bf(f.z);
            Bs[nn + 3][kk] = f2bf(f.w);
        }
        __syncthreads();
#pragma unroll
        for (int ks = 0; ks < 64; ks += 32) {
            bf16x8 a0 = *(const bf16x8*)&As[wm + l15][ks + quad * 8];
            bf16x8 a1 = *(const bf16x8*)&As[wm + 16 + l15][ks + quad * 8];
            bf16x8 b0 = *(const bf16x8*)&Bs[wn + l15][ks + quad * 8];
            bf16x8 b1 = *(const bf16x8*)&Bs[wn + 16 + l15][ks + quad * 8];
            acc[0][0] = MFMA16(a0, b0, acc[0][0]);
            acc[0][1] = MFMA16(a0, b1, acc[0][1]);
            acc[1][0] = MFMA16(a1, b0, acc[1][0]);
            acc[1][1] = MFMA16(a1, b1, acc[1][1]);
        }
        __syncthreads();
    }
    // epilogue: C[row = quad*4+r][col = l15] per 16x16 tile
#pragma unroll
    for (int i = 0; i < 2; ++i)
#pragma unroll
        for (int j = 0; j < 2; ++j)
#pragma unroll
            for (int r = 0; r < 4; ++r) {
                int row = m0 + wm + i * 16 + quad * 4 + r;
                int col = n0 + wn + j * 16 + l15;
                C[(size_t)row * N + col] = acc[i][j][r];
            }
}

// One block per (b, h, 64-row Q tile). Two-pass softmax.
// qkv: [B*L][3*D] fp32; bias: [B][L] fp32; align_out: [B*H][Lk][Lq] fp32;
// context: [B*L][D] fp32
__global__ __launch_bounds__(256) void attn_kernel(
    const float* __restrict__ qkv,
    const float* __restrict__ bias,
    float* __restrict__ align_out,
    float* __restrict__ context)
{
    __shared__ unsigned short Qs[64][72];
    __shared__ unsigned short Ks[64][72];
    __shared__ unsigned short Vt[64][72];  // Vt[d][key]
    __shared__ unsigned short Pa[64][72];  // Pa[q][key]  (A-frag for P*V)
    __shared__ float Pt[64][68];           // Pt[key][q]  (for align, fp32)

    const int tid  = threadIdx.x;
    const int lane = tid & 63, wave = tid >> 6;
    const int l15  = lane & 15, quad = lane >> 4;
    const int bh = blockIdx.x >> 5;      // 0..31
    const int qt = blockIdx.x & 31;      // 0..31
    const int b  = bh >> 4, h = bh & 15;
    const int q0 = qt * 64;
    const size_t qkv_base = (size_t)b * LL * (3 * DD);
    const float scale = 0.125f;  // DH^-0.5

    // stage Q tile (rows q0..q0+63, cols h*64..h*64+63)
#pragma unroll
    for (int i = 0; i < 4; ++i) {
        int v = tid + i * 256;
        int row = v >> 4, dv = (v & 15) * 4;
        float4 f = *(const float4*)&qkv[qkv_base + (size_t)(q0 + row) * (3 * DD) + h * DHD + dv];
        *(ull*)&Qs[row][dv] = pack4(f.x, f.y, f.z, f.w);
    }
    __syncthreads();

    // per-wave Q fragments (strip of 16 q-rows)
    bf16x8 aq0 = *(const bf16x8*)&Qs[wave * 16 + l15][quad * 8];
    bf16x8 aq1 = *(const bf16x8*)&Qs[wave * 16 + l15][32 + quad * 8];

    float m_[4], l_[4];
#pragma unroll
    for (int r = 0; r < 4; ++r) { m_[r] = -1e30f; l_[r] = 0.f; }

    // ---------- pass 1: online row max + sumexp ----------
    for (int kt = 0; kt < 32; ++kt) {
        __syncthreads();
#pragma unroll
        for (int i = 0; i < 4; ++i) {
            int v = tid + i * 256;
            int row = v >> 4, dv = (v & 15) * 4;
            float4 f = *(const float4*)&qkv[qkv_base + (size_t)(kt * 64 + row) * (3 * DD) + DD + h * DHD + dv];
            *(ull*)&Ks[row][dv] = pack4(f.x, f.y, f.z, f.w);
        }
        __syncthreads();

        float Sv[4][4];
#pragma unroll
        for (int j = 0; j < 4; ++j) {
            f32x4 s = (f32x4){0.f, 0.f, 0.f, 0.f};
            bf16x8 bk0 = *(const bf16x8*)&Ks[j * 16 + l15][quad * 8];
            bf16x8 bk1 = *(const bf16x8*)&Ks[j * 16 + l15][32 + quad * 8];
            s = MFMA16(aq0, bk0, s);
            s = MFMA16(aq1, bk1, s);
            float bv = bias[b * LL + kt * 64 + j * 16 + l15];
#pragma unroll
            for (int r = 0; r < 4; ++r) Sv[j][r] = s[r] * scale + bv;
        }
#pragma unroll
        for (int r = 0; r < 4; ++r) {
            float tm = fmaxf(fmaxf(Sv[0][r], Sv[1][r]), fmaxf(Sv[2][r], Sv[3][r]));
#pragma unroll
            for (int off = 1; off < 16; off <<= 1) tm = fmaxf(tm, __shfl_xor(tm, off));
            float ts = 0.f;
#pragma unroll
            for (int j = 0; j < 4; ++j) ts += __expf(Sv[j][r] - tm);
#pragma unroll
            for (int off = 1; off < 16; off <<= 1) ts += __shfl_xor(ts, off);
            float mn = fmaxf(m_[r], tm);
            l_[r] = l_[r] * __expf(m_[r] - mn) + ts * __expf(tm - mn);
            m_[r] = mn;
        }
    }

    float rl[4];
#pragma unroll
    for (int r = 0; r < 4; ++r) rl[r] = 1.f / l_[r];

    f32x4 ctx[4];
#pragma unroll
    for (int j = 0; j < 4; ++j) ctx[j] = (f32x4){0.f, 0.f, 0.f, 0.f};

    // ---------- pass 2: recompute S, write align, accumulate context ----------
    for (int kt = 0; kt < 32; ++kt) {
        __syncthreads();
        // stage K tile
#pragma unroll
        for (int i = 0; i < 4; ++i) {
            int v = tid + i * 256;
            int row = v >> 4, dv = (v & 15) * 4;
            float4 f = *(const float4*)&qkv[qkv_base + (size_t)(kt * 64 + row) * (3 * DD) + DD + h * DHD + dv];
            *(ull*)&Ks[row][dv] = pack4(f.x, f.y, f.z, f.w);
        }
        // stage V tile transposed: Vt[d][key]
#pragma unroll
        for (int i = 0; i < 4; ++i) {
            int v = tid + i * 256;
            int kk = v >> 4, dv = (v & 15) * 4;
            float4 f = *(const float4*)&qkv[qkv_base + (size_t)(kt * 64 + kk) * (3 * DD) + 2 * DD + h * DHD + dv];
            Vt[dv + 0][kk] = f2bf(f.x);
            Vt[dv + 1][kk] = f2bf(f.y);
            Vt[dv + 2][kk] = f2bf(f.z);
            Vt[dv + 3][kk] = f2bf(f.w);
        }
        __syncthreads();

#pragma unroll
        for (int j = 0; j < 4; ++j) {
            f32x4 s = (f32x4){0.f, 0.f, 0.f, 0.f};
            bf16x8 bk0 = *(const bf16x8*)&Ks[j * 16 + l15][quad * 8];
            bf16x8 bk1 = *(const bf16x8*)&Ks[j * 16 + l15][32 + quad * 8];
            s = MFMA16(aq0, bk0, s);
            s = MFMA16(aq1, bk1, s);
            float bv = bias[b * LL + kt * 64 + j * 16 + l15];
#pragma unroll
            for (int r = 0; r < 4; ++r) {
                float p = __expf(s[r] * scale + bv - m_[r]) * rl[r];
                int kl = j * 16 + l15;              // key local
                int ql = wave * 16 + quad * 4 + r;  // q local
                Pt[kl][ql] = p;
                Pa[ql][kl] = f2bf(p);
            }
        }
        __syncthreads();

        // coalesced align write: align[bh][key][q]  (fp32 float4)
#pragma unroll
        for (int i = 0; i < 4; ++i) {
            int v = tid + i * 256;
            int kl = v >> 4, qv = (v & 15) * 4;
            float4 f = *(const float4*)&Pt[kl][qv];
            *(float4*)&align_out[((size_t)bh * LL + kt * 64 + kl) * LL + q0 + qv] = f;
        }

        // context += P * V
#pragma unroll
        for (int ks = 0; ks < 64; ks += 32) {
            bf16x8 ap = *(const bf16x8*)&Pa[wave * 16 + l15][ks + quad * 8];
#pragma unroll
            for (int j = 0; j < 4; ++j) {
                bf16x8 bv = *(const bf16x8*)&Vt[j * 16 + l15][ks + quad * 8];
                ctx[j] = MFMA16(ap, bv, ctx[j]);
            }
        }
    }

    // write context [B*L][D] (combined heads), fp32
#pragma unroll
    for (int j = 0; j < 4; ++j)
#pragma unroll
        for (int r = 0; r < 4; ++r) {
            int ql = wave * 16 + quad * 4 + r;
            int dv = j * 16 + l15;
            context[(size_t)(b * LL + q0 + ql) * DD + h * DHD + dv] = ctx[j][r];
        }
}

extern "C" void kernel_launch(void* const* d_in, const int* in_sizes, int n_in,
                              void* d_out, int out_size, void* d_ws, size_t ws_size,
                              hipStream_t stream) {
    const float* queries = (const float*)d_in[0];
    const float* bias    = (const float*)d_in[1];
    const float* w_qkv   = (const float*)d_in[2];
    const float* w_o     = (const float*)d_in[3];

    float* out_p   = (float*)d_out;
    float* align_p = out_p + (size_t)BB * LL * DD;

    float* qkv = (float*)d_ws;                       // [4096][3072] fp32
    float* ctx = qkv + (size_t)BB * LL * 3 * DD;     // [4096][1024] fp32

    // 1) qkv = queries @ w_qkv   (M=4096, N=3072, K=1024)
    gemm_f32<<<dim3((3 * DD) / 64, (BB * LL) / 64), 256, 0, stream>>>(
        queries, w_qkv, qkv, BB * LL, 3 * DD, DD);

    // 2) attention: align + context
    attn_kernel<<<dim3(BB * HH * (LL / 64)), 256, 0, stream>>>(
        qkv, bias, align_p, ctx);

    // 3) out = ctx @ w_o   (M=4096, N=1024, K=1024)
    gemm_f32<<<dim3(DD / 64, (BB * LL) / 64), 256, 0, stream>>>(
        ctx, w_o, out_p, BB * LL, DD, DD);
}